// Round 4
// baseline (296.384 us; speedup 1.0000x reference)
//
#include <hip/hip_runtime.h>
#include <stdint.h>

#define HID 1024
#define SEQ 2048
#define NB 2
#define NH 16
#define HD 64
#define MROWS 4096  // NB*SEQ

typedef float f32x4 __attribute__((ext_vector_type(4)));
typedef short s16x4 __attribute__((ext_vector_type(4)));
typedef short s16x8 __attribute__((ext_vector_type(8)));

#define MFMA16(a, b, c) __builtin_amdgcn_mfma_f32_16x16x32_bf16((a), (b), (c), 0, 0, 0)

#define GLOAD_LDS16(gp, lp)                                                    \
  __builtin_amdgcn_global_load_lds(                                            \
      (const __attribute__((address_space(1))) unsigned int*)(gp),             \
      (__attribute__((address_space(3))) unsigned int*)(lp), 16, 0, 0)

__device__ __forceinline__ short f2bf(float x) {
  uint32_t u = __builtin_bit_cast(uint32_t, x);
  u += 0x7fffu + ((u >> 16) & 1u);
  return (short)(u >> 16);
}

// ---------------- cast X: f32 -> bf16, 8 elems/thread ----------------
__global__ __launch_bounds__(256) void cast_x_kernel(const float* __restrict__ src,
                                                     short* __restrict__ dst) {
  const size_t i = (size_t)blockIdx.x * 256 + threadIdx.x;
  const float* s = src + i * 8;
  f32x4 a = *(const f32x4*)(s);
  f32x4 b = *(const f32x4*)(s + 4);
  s16x8 o;
  o[0] = f2bf(a[0]); o[1] = f2bf(a[1]); o[2] = f2bf(a[2]); o[3] = f2bf(a[3]);
  o[4] = f2bf(b[0]); o[5] = f2bf(b[1]); o[6] = f2bf(b[2]); o[7] = f2bf(b[3]);
  *(s16x8*)(dst + i * 8) = o;
}

// -- fused transpose-cast: 4x W[k][n] f32 -> Wt[n][k] bf16 (1024x1024 each) --
__global__ __launch_bounds__(256) void transpose_cast4_kernel(
    const float* __restrict__ w0, const float* __restrict__ w1,
    const float* __restrict__ w2, const float* __restrict__ w3,
    short* __restrict__ dstall) {
  __shared__ float t[32][33];
  const int z = blockIdx.z;
  const float* src = (z == 0) ? w0 : (z == 1) ? w1 : (z == 2) ? w2 : w3;
  short* dst = dstall + ((size_t)z << 20);
  const int tx = threadIdx.x & 31, ty = threadIdx.x >> 5;
  const int r0 = blockIdx.y * 32, c0 = blockIdx.x * 32;
#pragma unroll
  for (int i = 0; i < 4; i++)
    t[ty + i * 8][tx] = src[(size_t)(r0 + ty + i * 8) * HID + c0 + tx];
  __syncthreads();
#pragma unroll
  for (int i = 0; i < 4; i++)
    dst[(size_t)(c0 + ty + i * 8) * HID + r0 + tx] = f2bf(t[tx][ty + i * 8]);
}

// ---------------- bf16 GEMM: C = A[M][1024] * Bt[N][1024]^T ----------------
// 128x128 tile, BK=32, 4 waves (2x2), 16x16x32 MFMA, global_load_lds staging.
// EPI 0: QKV epilogue (bias + scatter to Qb/Kb [bh][s][d], Vt [bh][d][s_perm])
// EPI 1: proj epilogue (bias + f32 out [m][1024])
template <int EPI>
__global__ __launch_bounds__(256) void gemm_bf16(
    const short* __restrict__ A, const short* __restrict__ Bt,
    const float* __restrict__ b0, const float* __restrict__ b1,
    const float* __restrict__ b2, short* __restrict__ Qb, short* __restrict__ Kb,
    short* __restrict__ Vt, float* __restrict__ Out) {
  __shared__ char lds[16384];  // A tile [128][32] @0, B tile [128][32] @8192
  const int tid = threadIdx.x;
  const int w = tid >> 6, l = tid & 63, lg = l >> 4, ln = l & 15;
  const int wm = w >> 1, wn = w & 1;
  const int m0 = blockIdx.y * 128, n0 = blockIdx.x * 128;

  f32x4 acc[4][4];
#pragma unroll
  for (int i = 0; i < 4; i++)
#pragma unroll
    for (int j = 0; j < 4; j++) acc[i][j] = f32x4{0.f, 0.f, 0.f, 0.f};

  for (int k0 = 0; k0 < 1024; k0 += 32) {
    __syncthreads();  // protect LDS from prior-iter readers
#pragma unroll
    for (int i = 0; i < 2; i++) {
      const int chunk = (w * 2 + i) * 64 + l;  // 16B chunk id, 4 chunks/row
      const int row = chunk >> 2;
      const int cs = (chunk & 3) ^ (row & 3);  // source-side XOR swizzle
      GLOAD_LDS16(A + (size_t)(m0 + row) * 1024 + k0 + cs * 8,
                  lds + (w * 2 + i) * 1024);
      GLOAD_LDS16(Bt + (size_t)(n0 + row) * 1024 + k0 + cs * 8,
                  lds + 8192 + (w * 2 + i) * 1024);
    }
    __syncthreads();  // compiler emits vmcnt(0) before barrier

    s16x8 af[4], bfr[4];
#pragma unroll
    for (int mi = 0; mi < 4; mi++) {
      const int row = wm * 64 + mi * 16 + ln;
      af[mi] = *(const s16x8*)(lds + row * 64 + ((lg ^ (row & 3)) * 16));
    }
#pragma unroll
    for (int ni = 0; ni < 4; ni++) {
      const int row = wn * 64 + ni * 16 + ln;
      bfr[ni] = *(const s16x8*)(lds + 8192 + row * 64 + ((lg ^ (row & 3)) * 16));
    }
#pragma unroll
    for (int mi = 0; mi < 4; mi++)
#pragma unroll
      for (int ni = 0; ni < 4; ni++)
        acc[mi][ni] = MFMA16(af[mi], bfr[ni], acc[mi][ni]);
  }

  // epilogue: C/D layout row=(lane>>4)*4+reg, col=lane&15
#pragma unroll
  for (int ni = 0; ni < 4; ni++) {
    const int c = n0 + wn * 64 + ni * 16 + ln;
    if (EPI == 0) {
      const int mat = c >> 10, cc = c & 1023, hh = cc >> 6, d = cc & 63;
      const float* bp = (mat == 0) ? b0 : (mat == 1) ? b1 : b2;
      const float bias = bp[cc];
#pragma unroll
      for (int mi = 0; mi < 4; mi++) {
#pragma unroll
        for (int r = 0; r < 4; r++) {
          const int m = m0 + wm * 64 + mi * 16 + lg * 4 + r;
          const int bb = m >> 11, s = m & 2047;
          const short v = f2bf(acc[mi][ni][r] + bias);
          const size_t bh = (size_t)(bb * 16 + hh);
          if (mat == 0)
            Qb[(bh * SEQ + s) * HD + d] = v;
          else if (mat == 1)
            Kb[(bh * SEQ + s) * HD + d] = v;
          else {
            // kappa-permute s within its 32-group so attn PV loads are 16B:
            // slot = ((s&15)>>2)*8 + ((s>>4)&1)*4 + (s&3)
            const int sp = (s & ~31) | ((s & 12) << 1) | (((s >> 4) & 1) << 2) |
                           (s & 3);
            Vt[(bh * HD + d) * SEQ + sp] = v;
          }
        }
      }
    } else {
      const float bias = b0[c];
#pragma unroll
      for (int mi = 0; mi < 4; mi++)
#pragma unroll
        for (int r = 0; r < 4; r++) {
          const int m = m0 + wm * 64 + mi * 16 + lg * 4 + r;
          Out[(size_t)m * 1024 + c] = acc[mi][ni][r] + bias;
        }
    }
  }
}

// ---------------- flash attention (causal), split-KV wave pairs ----------------
// 4096 waves: each (bh, rb-pair) task is handled by TWO waves splitting the KV
// range (wave A = front half, wave B = back half + masked diagonal), merged via
// LDS (flash-decoding algebra). Wave-level pairing rb / 127-rb balances causal
// work. S^T = mfma(K,Q): lane owns query col q=ln; softmax per-lane; P feeds PV
// B-operand with no cross-lane movement (V stored kappa-permuted).

__device__ __forceinline__ void load_ktile(const short* Kbase, int k0, int ln,
                                           int lg, s16x8 kf[4][2]) {
#pragma unroll
  for (int mt = 0; mt < 4; mt++) {
    const short* Kp = Kbase + (size_t)(k0 + mt * 16 + ln) * HD + lg * 8;
    kf[mt][0] = *(const s16x8*)(Kp);
    kf[mt][1] = *(const s16x8*)(Kp + 32);
  }
}

__device__ __forceinline__ void load_vtile(const short* Vbase, int k0, int ln,
                                           int lg, s16x8 vf[2][4]) {
#pragma unroll
  for (int s = 0; s < 2; s++)
#pragma unroll
    for (int vmt = 0; vmt < 4; vmt++) {
      const short* Vp = Vbase + (size_t)(vmt * 16 + ln) * SEQ + k0 + s * 32 + lg * 8;
      vf[s][vmt] = *(const s16x8*)(Vp);
    }
}

template <bool MASK>
__device__ __forceinline__ void softmax_pv(f32x4 st[4], const s16x8 vf[2][4],
                                           f32x4 o[4], float& m2, float& l_run,
                                           int k0, int qrow, int lg) {
  const float SC = 0.18033688011112042f;  // (1/8) * log2(e)
  float p[4][4];
  float pmax = -3e38f;
#pragma unroll
  for (int mt = 0; mt < 4; mt++)
#pragma unroll
    for (int r = 0; r < 4; r++) {
      float v = st[mt][r] * SC;
      if (MASK) {
        const int key = k0 + mt * 16 + lg * 4 + r;
        if (key > qrow) v = -3e38f;
      }
      p[mt][r] = v;
      pmax = fmaxf(pmax, v);
    }
  pmax = fmaxf(pmax, __shfl_xor(pmax, 16));
  pmax = fmaxf(pmax, __shfl_xor(pmax, 32));
  const float m_new = fmaxf(m2, pmax);
  const float corr = exp2f(m2 - m_new);
  float psum = 0.f;
#pragma unroll
  for (int mt = 0; mt < 4; mt++)
#pragma unroll
    for (int r = 0; r < 4; r++) {
      const float e = exp2f(p[mt][r] - m_new);
      p[mt][r] = e;
      psum += e;
    }
  psum += __shfl_xor(psum, 16);
  psum += __shfl_xor(psum, 32);
  l_run = l_run * corr + psum;
  m2 = m_new;
#pragma unroll
  for (int i = 0; i < 4; i++) o[i] *= corr;

  s16x8 pf[2];
#pragma unroll
  for (int s = 0; s < 2; s++)
#pragma unroll
    for (int h = 0; h < 2; h++)
#pragma unroll
      for (int r = 0; r < 4; r++) pf[s][h * 4 + r] = f2bf(p[s * 2 + h][r]);
#pragma unroll
  for (int s = 0; s < 2; s++)
#pragma unroll
    for (int vmt = 0; vmt < 4; vmt++)
      o[vmt] = MFMA16(vf[s][vmt], pf[s], o[vmt]);
}

// process KV tiles [t0, t1); if MASK_LAST, tile t1-1 applies the causal mask
template <bool MASK_LAST>
__device__ __forceinline__ void flash_range(const short* Kbase,
                                            const short* Vbase,
                                            const s16x8& qf0, const s16x8& qf1,
                                            int t0, int t1, int qrow, int lg,
                                            int ln, float& m2, float& l_run,
                                            f32x4 o[4]) {
  if (t0 >= t1) return;
  s16x8 kcur[4][2];
  load_ktile(Kbase, t0 * 64, ln, lg, kcur);
  for (int kt = t0; kt < t1 - 1; ++kt) {
    f32x4 st[4];
#pragma unroll
    for (int mt = 0; mt < 4; mt++) {
      st[mt] = f32x4{0.f, 0.f, 0.f, 0.f};
      st[mt] = MFMA16(kcur[mt][0], qf0, st[mt]);
      st[mt] = MFMA16(kcur[mt][1], qf1, st[mt]);
    }
    s16x8 knext[4][2];
    load_ktile(Kbase, (kt + 1) * 64, ln, lg, knext);  // prefetch next K
    s16x8 vf[2][4];
    load_vtile(Vbase, kt * 64, ln, lg, vf);  // issue V before softmax
    softmax_pv<false>(st, vf, o, m2, l_run, kt * 64, qrow, lg);
#pragma unroll
    for (int mt = 0; mt < 4; mt++) {
      kcur[mt][0] = knext[mt][0];
      kcur[mt][1] = knext[mt][1];
    }
  }
  {  // last tile of range
    f32x4 st[4];
#pragma unroll
    for (int mt = 0; mt < 4; mt++) {
      st[mt] = f32x4{0.f, 0.f, 0.f, 0.f};
      st[mt] = MFMA16(kcur[mt][0], qf0, st[mt]);
      st[mt] = MFMA16(kcur[mt][1], qf1, st[mt]);
    }
    s16x8 vf[2][4];
    load_vtile(Vbase, (t1 - 1) * 64, ln, lg, vf);
    softmax_pv<MASK_LAST>(st, vf, o, m2, l_run, (t1 - 1) * 64, qrow, lg);
  }
}

// one query row-block rb, split across a wave pair (half 0/1), merged via LDS
__device__ __forceinline__ void attn_task(const short* __restrict__ Qb,
                                          const short* Kbase, const short* Vbase,
                                          short* __restrict__ Ob, int bh, int rb,
                                          int task, int half, int l,
                                          float (*sm_m)[64], float (*sm_l)[64],
                                          float (*sm_o)[16][64]) {
  const int lg = l >> 4, ln = l & 15;
  const int qrow = rb * 16 + ln;
  const short* Qp = Qb + ((size_t)bh * SEQ + qrow) * HD;
  const s16x8 qf0 = *(const s16x8*)(Qp + lg * 8);
  const s16x8 qf1 = *(const s16x8*)(Qp + 32 + lg * 8);

  float m2 = -3e38f, l_run = 0.f;
  f32x4 o[4];
#pragma unroll
  for (int i = 0; i < 4; i++) o[i] = f32x4{0.f, 0.f, 0.f, 0.f};

  const int nt = (rb >> 2) + 1;  // total KV tiles incl. diagonal
  const int ntA = nt >> 1;       // front half (never contains diagonal)

  if (half == 1) {
    flash_range<true>(Kbase, Vbase, qf0, qf1, ntA, nt, qrow, lg, ln, m2, l_run, o);
    sm_m[task][l] = m2;
    sm_l[task][l] = l_run;
#pragma unroll
    for (int mt = 0; mt < 4; mt++)
#pragma unroll
      for (int r = 0; r < 4; r++) sm_o[task][mt * 4 + r][l] = o[mt][r];
  } else {
    flash_range<false>(Kbase, Vbase, qf0, qf1, 0, ntA, qrow, lg, ln, m2, l_run, o);
  }
  __syncthreads();
  if (half == 0) {
    const float mB = sm_m[task][l], lB = sm_l[task][l];
    const float m_new = fmaxf(m2, mB);
    const float cA = exp2f(m2 - m_new), cB = exp2f(mB - m_new);
    const float inv = 1.0f / (l_run * cA + lB * cB);
    const int bb = bh >> 4, hh = bh & 15;
    const size_t orow = (size_t)(bb * SEQ + qrow) * HID + hh * HD;
#pragma unroll
    for (int mt = 0; mt < 4; mt++) {
      s16x4 ov;
#pragma unroll
      for (int r = 0; r < 4; r++)
        ov[r] = f2bf((o[mt][r] * cA + sm_o[task][mt * 4 + r][l] * cB) * inv);
      *(s16x4*)(Ob + orow + mt * 16 + lg * 4) = ov;
    }
  }
  __syncthreads();  // protect LDS before next task's publish
}

__global__ __launch_bounds__(256) void attn_kernel(const short* __restrict__ Qb,
                                                   const short* __restrict__ Kb,
                                                   const short* __restrict__ Vt,
                                                   short* __restrict__ Ob) {
  __shared__ float sm_m[2][64], sm_l[2][64], sm_o[2][16][64];
  const int bh = blockIdx.y;
  const int w = threadIdx.x >> 6, l = threadIdx.x & 63;
  const int task = w >> 1, half = w & 1;
  const int pi = blockIdx.x * 2 + task;  // [0,64)
  const short* Kbase = Kb + (size_t)bh * (SEQ * HD);
  const short* Vbase = Vt + (size_t)bh * (HD * SEQ);
  attn_task(Qb, Kbase, Vbase, Ob, bh, pi, task, half, l, sm_m, sm_l, sm_o);
  attn_task(Qb, Kbase, Vbase, Ob, bh, 127 - pi, task, half, l, sm_m, sm_l, sm_o);
}

// ---------------- launch ----------------
extern "C" void kernel_launch(void* const* d_in, const int* in_sizes, int n_in,
                              void* d_out, int out_size, void* d_ws,
                              size_t ws_size, hipStream_t stream) {
  const float* X = (const float*)d_in[0];
  // d_in[1] = mask (causal, implemented directly)
  const float* Wq = (const float*)d_in[2];
  const float* bq = (const float*)d_in[3];
  const float* Wk = (const float*)d_in[4];
  const float* bk = (const float*)d_in[5];
  const float* Wv = (const float*)d_in[6];
  const float* bv = (const float*)d_in[7];
  const float* Wo = (const float*)d_in[8];
  const float* bo = (const float*)d_in[9];
  float* out = (float*)d_out;

  char* ws = (char*)d_ws;
  short* Xb = (short*)(ws);                  // 8 MB  [4096][1024]
  short* Wtall = (short*)(ws + (8u << 20));  // 8 MB  (Wq|Wk|Wv|Wo)^T bf16
  short* Qb = (short*)(ws + (16u << 20));    // 8 MB  [32][2048][64]
  short* Kb = (short*)(ws + (24u << 20));    // 8 MB
  short* Vt = (short*)(ws + (32u << 20));    // 8 MB  [32][64][2048] kappa-perm
  short* Ob = (short*)(ws + (40u << 20));    // 8 MB  [4096][1024]
  short* Wto = Wtall + (3u << 20);

  cast_x_kernel<<<2048, 256, 0, stream>>>(X, Xb);
  transpose_cast4_kernel<<<dim3(32, 32, 4), 256, 0, stream>>>(Wq, Wk, Wv, Wo,
                                                              Wtall);

  gemm_bf16<0><<<dim3(24, 32), 256, 0, stream>>>(Xb, Wtall, bq, bk, bv, Qb, Kb,
                                                 Vt, nullptr);
  attn_kernel<<<dim3(32, 32), 256, 0, stream>>>(Qb, Kb, Vt, Ob);
  gemm_bf16<1><<<dim3(8, 32), 256, 0, stream>>>(Ob, Wto, bo, nullptr, nullptr,
                                                nullptr, nullptr, nullptr, out);
}

// Round 6
// 237.975 us; speedup vs baseline: 1.2454x; 1.2454x over previous
//
#include <hip/hip_runtime.h>
#include <stdint.h>

#define HID 1024
#define SEQ 2048
#define NB 2
#define NH 16
#define HD 64
#define MROWS 4096  // NB*SEQ

typedef float f32x4 __attribute__((ext_vector_type(4)));
typedef short s16x4 __attribute__((ext_vector_type(4)));
typedef short s16x8 __attribute__((ext_vector_type(8)));

#define MFMA16(a, b, c) __builtin_amdgcn_mfma_f32_16x16x32_bf16((a), (b), (c), 0, 0, 0)

#define GLOAD_LDS16(gp, lp)                                                    \
  __builtin_amdgcn_global_load_lds(                                            \
      (const __attribute__((address_space(1))) unsigned int*)(gp),             \
      (__attribute__((address_space(3))) unsigned int*)(lp), 16, 0, 0)

__device__ __forceinline__ short f2bf(float x) {
  uint32_t u = __builtin_bit_cast(uint32_t, x);
  u += 0x7fffu + ((u >> 16) & 1u);
  return (short)(u >> 16);
}

// ---------------- cast X: f32 -> bf16, 8 elems/thread ----------------
__global__ __launch_bounds__(256) void cast_x_kernel(const float* __restrict__ src,
                                                     short* __restrict__ dst) {
  const size_t i = (size_t)blockIdx.x * 256 + threadIdx.x;
  const float* s = src + i * 8;
  f32x4 a = *(const f32x4*)(s);
  f32x4 b = *(const f32x4*)(s + 4);
  s16x8 o;
  o[0] = f2bf(a[0]); o[1] = f2bf(a[1]); o[2] = f2bf(a[2]); o[3] = f2bf(a[3]);
  o[4] = f2bf(b[0]); o[5] = f2bf(b[1]); o[6] = f2bf(b[2]); o[7] = f2bf(b[3]);
  *(s16x8*)(dst + i * 8) = o;
}

// -- fused transpose-cast: 4x W[k][n] f32 -> Wt[n][k] bf16 (1024x1024 each) --
__global__ __launch_bounds__(256) void transpose_cast4_kernel(
    const float* __restrict__ w0, const float* __restrict__ w1,
    const float* __restrict__ w2, const float* __restrict__ w3,
    short* __restrict__ dstall) {
  __shared__ float t[32][33];
  const int z = blockIdx.z;
  const float* src = (z == 0) ? w0 : (z == 1) ? w1 : (z == 2) ? w2 : w3;
  short* dst = dstall + ((size_t)z << 20);
  const int tx = threadIdx.x & 31, ty = threadIdx.x >> 5;
  const int r0 = blockIdx.y * 32, c0 = blockIdx.x * 32;
#pragma unroll
  for (int i = 0; i < 4; i++)
    t[ty + i * 8][tx] = src[(size_t)(r0 + ty + i * 8) * HID + c0 + tx];
  __syncthreads();
#pragma unroll
  for (int i = 0; i < 4; i++)
    dst[(size_t)(c0 + ty + i * 8) * HID + r0 + tx] = f2bf(t[tx][ty + i * 8]);
}

// ---------------- bf16 GEMM: C = A[M][1024] * Bt[N][1024]^T ----------------
// 128x128 tile, BK=32, 4 waves (2x2), 16x16x32 MFMA, global_load_lds staging.
// EPI 0: QKV epilogue: bias + scatter.
//   Q -> Qb [bh][s][d]
//   K -> Kg [bh][tile][64x64 image]: off = r*64 + ((d/8 ^ (r&7))*8) + d%8
//        (r = s%64; chunk-swizzled so attn ds_read_b128 is bank-minimal)
//   V -> Vg [bh][tile][64x64 image]: kappa-permuted key slot kp, then
//        off = d*64 + ((kp/8 ^ (d&7))*8) + kp%8
// EPI 1: proj epilogue (bias + f32 out [m][1024])
template <int EPI>
__global__ __launch_bounds__(256) void gemm_bf16(
    const short* __restrict__ A, const short* __restrict__ Bt,
    const float* __restrict__ b0, const float* __restrict__ b1,
    const float* __restrict__ b2, short* __restrict__ Qb, short* __restrict__ Kg,
    short* __restrict__ Vg, float* __restrict__ Out) {
  __shared__ char lds[16384];  // A tile [128][32] @0, B tile [128][32] @8192
  const int tid = threadIdx.x;
  const int w = tid >> 6, l = tid & 63, lg = l >> 4, ln = l & 15;
  const int wm = w >> 1, wn = w & 1;
  const int m0 = blockIdx.y * 128, n0 = blockIdx.x * 128;

  f32x4 acc[4][4];
#pragma unroll
  for (int i = 0; i < 4; i++)
#pragma unroll
    for (int j = 0; j < 4; j++) acc[i][j] = f32x4{0.f, 0.f, 0.f, 0.f};

  for (int k0 = 0; k0 < 1024; k0 += 32) {
    __syncthreads();  // protect LDS from prior-iter readers
#pragma unroll
    for (int i = 0; i < 2; i++) {
      const int chunk = (w * 2 + i) * 64 + l;  // 16B chunk id, 4 chunks/row
      const int row = chunk >> 2;
      const int cs = (chunk & 3) ^ (row & 3);  // source-side XOR swizzle
      GLOAD_LDS16(A + (size_t)(m0 + row) * 1024 + k0 + cs * 8,
                  lds + (w * 2 + i) * 1024);
      GLOAD_LDS16(Bt + (size_t)(n0 + row) * 1024 + k0 + cs * 8,
                  lds + 8192 + (w * 2 + i) * 1024);
    }
    __syncthreads();  // compiler emits vmcnt(0) before barrier

    s16x8 af[4], bfr[4];
#pragma unroll
    for (int mi = 0; mi < 4; mi++) {
      const int row = wm * 64 + mi * 16 + ln;
      af[mi] = *(const s16x8*)(lds + row * 64 + ((lg ^ (row & 3)) * 16));
    }
#pragma unroll
    for (int ni = 0; ni < 4; ni++) {
      const int row = wn * 64 + ni * 16 + ln;
      bfr[ni] = *(const s16x8*)(lds + 8192 + row * 64 + ((lg ^ (row & 3)) * 16));
    }
#pragma unroll
    for (int mi = 0; mi < 4; mi++)
#pragma unroll
      for (int ni = 0; ni < 4; ni++)
        acc[mi][ni] = MFMA16(af[mi], bfr[ni], acc[mi][ni]);
  }

  // epilogue: C/D layout row=(lane>>4)*4+reg, col=lane&15
#pragma unroll
  for (int ni = 0; ni < 4; ni++) {
    const int c = n0 + wn * 64 + ni * 16 + ln;
    if (EPI == 0) {
      const int mat = c >> 10, cc = c & 1023, hh = cc >> 6, d = cc & 63;
      const float* bp = (mat == 0) ? b0 : (mat == 1) ? b1 : b2;
      const float bias = bp[cc];
#pragma unroll
      for (int mi = 0; mi < 4; mi++) {
#pragma unroll
        for (int r = 0; r < 4; r++) {
          const int m = m0 + wm * 64 + mi * 16 + lg * 4 + r;
          const int bb = m >> 11, s = m & 2047;
          const short v = f2bf(acc[mi][ni][r] + bias);
          const size_t bh = (size_t)(bb * 16 + hh);
          if (mat == 0) {
            Qb[(bh * SEQ + s) * HD + d] = v;
          } else if (mat == 1) {
            const int tile = s >> 6, rr = s & 63;
            Kg[bh * (SEQ * HD) + tile * 4096 + rr * 64 +
               ((((d >> 3) ^ (rr & 7)) << 3) | (d & 7))] = v;
          } else {
            // kappa-permute s within its 32-group (PV frag key order):
            const int sp = (s & ~31) | ((s & 12) << 1) | (((s >> 4) & 1) << 2) |
                           (s & 3);
            const int tile = sp >> 6, kp = sp & 63;
            Vg[bh * (SEQ * HD) + tile * 4096 + d * 64 +
               ((((kp >> 3) ^ (d & 7)) << 3) | (kp & 7))] = v;
          }
        }
      }
    } else {
      const float bias = b0[c];
#pragma unroll
      for (int mi = 0; mi < 4; mi++)
#pragma unroll
        for (int r = 0; r < 4; r++) {
          const int m = m0 + wm * 64 + mi * 16 + lg * 4 + r;
          Out[(size_t)m * 1024 + c] = acc[mi][ni][r] + bias;
        }
    }
  }
}

// ------------- flash attention (causal), block-cooperative LDS pipeline -------------
// 512 blocks (XCD-swizzled), 4 waves/block. Block owns a 64-row Q group; all
// waves iterate the SAME KV tiles, staged K+V (16KB) into double-buffered LDS
// via global_load_lds. Raw s_barrier + counted vmcnt(4) keeps next-tile loads
// in flight across barriers (depth-1 async pipeline). Causal pairing (g, 31-g)
// = 33 staged tiles per block, perfectly balanced.

__device__ __forceinline__ void stage_tile(const short* Kt, const short* Vt,
                                           int t, char* buf, int w, int l) {
  // waves 0,1 stage the 8KB K image; waves 2,3 the 8KB V image (4x 1KB each)
  const char* src = (w < 2) ? ((const char*)(Kt + (size_t)t * 4096) + (w & 1) * 4096)
                            : ((const char*)(Vt + (size_t)t * 4096) + (w & 1) * 4096);
  char* dst = buf + ((w < 2) ? 0 : 8192) + (w & 1) * 4096;
#pragma unroll
  for (int j = 0; j < 4; j++)
    GLOAD_LDS16(src + j * 1024 + l * 16, dst + j * 1024);
}

template <bool MASK>
__device__ __forceinline__ void softmax_pv(f32x4 st[4], const s16x8 vf[2][4],
                                           f32x4 o[4], float& m2, float& l_run,
                                           int k0, int qrow, int lg) {
  const float SC = 0.18033688011112042f;  // (1/8) * log2(e)
  float p[4][4];
  float pmax = -3e38f;
#pragma unroll
  for (int mt = 0; mt < 4; mt++)
#pragma unroll
    for (int r = 0; r < 4; r++) {
      float v = st[mt][r] * SC;
      if (MASK) {
        const int key = k0 + mt * 16 + lg * 4 + r;
        if (key > qrow) v = -3e38f;
      }
      p[mt][r] = v;
      pmax = fmaxf(pmax, v);
    }
  pmax = fmaxf(pmax, __shfl_xor(pmax, 16));
  pmax = fmaxf(pmax, __shfl_xor(pmax, 32));
  const float m_new = fmaxf(m2, pmax);
  const float corr = exp2f(m2 - m_new);
  float psum = 0.f;
#pragma unroll
  for (int mt = 0; mt < 4; mt++)
#pragma unroll
    for (int r = 0; r < 4; r++) {
      const float e = exp2f(p[mt][r] - m_new);
      p[mt][r] = e;
      psum += e;
    }
  psum += __shfl_xor(psum, 16);
  psum += __shfl_xor(psum, 32);
  l_run = l_run * corr + psum;
  m2 = m_new;
#pragma unroll
  for (int i = 0; i < 4; i++) o[i] *= corr;

  s16x8 pf[2];
#pragma unroll
  for (int s = 0; s < 2; s++)
#pragma unroll
    for (int h = 0; h < 2; h++)
#pragma unroll
      for (int r = 0; r < 4; r++) pf[s][h * 4 + r] = f2bf(p[s * 2 + h][r]);
#pragma unroll
  for (int s = 0; s < 2; s++)
#pragma unroll
    for (int vmt = 0; vmt < 4; vmt++)
      o[vmt] = MFMA16(vf[s][vmt], pf[s], o[vmt]);
}

template <bool MASK>
__device__ __forceinline__ void compute_tile(const char* cbuf, const s16x8& qf0,
                                             const s16x8& qf1, int k0, int qrow,
                                             int lg, int ln, float& m2,
                                             float& l_run, f32x4 o[4]) {
  const int x = ln & 7;
  f32x4 st[4];
#pragma unroll
  for (int mt = 0; mt < 4; mt++) {
    const char* rowp = cbuf + (mt * 16 + ln) * 128;
    const s16x8 k0f = *(const s16x8*)(rowp + ((lg ^ x) * 16));
    const s16x8 k1f = *(const s16x8*)(rowp + (((4 + lg) ^ x) * 16));
    st[mt] = f32x4{0.f, 0.f, 0.f, 0.f};
    st[mt] = MFMA16(k0f, qf0, st[mt]);
    st[mt] = MFMA16(k1f, qf1, st[mt]);
  }
  s16x8 vf[2][4];
#pragma unroll
  for (int s = 0; s < 2; s++)
#pragma unroll
    for (int vmt = 0; vmt < 4; vmt++)
      vf[s][vmt] = *(const s16x8*)(cbuf + 8192 + (vmt * 16 + ln) * 128 +
                                   (((s * 4 + lg) ^ x) * 16));
  softmax_pv<MASK>(st, vf, o, m2, l_run, k0, qrow, lg);
}

__device__ __forceinline__ void attn_group_pass(const short* Kt, const short* Vt,
                                                const short* __restrict__ Qb,
                                                short* __restrict__ Ob, int bh,
                                                int G, int w, int l, char* lds) {
  const int lg = l >> 4, ln = l & 15;
  const int qrow = G * 64 + w * 16 + ln;
  const short* Qp = Qb + ((size_t)bh * SEQ + qrow) * HD;
  const s16x8 qf0 = *(const s16x8*)(Qp + lg * 8);
  const s16x8 qf1 = *(const s16x8*)(Qp + 32 + lg * 8);

  float m2 = -3e38f, l_run = 0.f;
  f32x4 o[4];
#pragma unroll
  for (int i = 0; i < 4; i++) o[i] = f32x4{0.f, 0.f, 0.f, 0.f};

  const int nt = G + 1;  // tiles 0..G; tile G is the masked diagonal
  stage_tile(Kt, Vt, 0, lds, w, l);
  for (int t = 0; t < nt - 1; ++t) {
    stage_tile(Kt, Vt, t + 1, lds + ((t + 1) & 1) * 16384, w, l);
    asm volatile("s_waitcnt vmcnt(4)" ::: "memory");  // tile t resident; t+1 in flight
    __builtin_amdgcn_s_barrier();
    __builtin_amdgcn_sched_barrier(0);
    compute_tile<false>(lds + (t & 1) * 16384, qf0, qf1, t * 64, qrow, lg, ln,
                        m2, l_run, o);
    __builtin_amdgcn_s_barrier();  // all waves done reading buf before overwrite
    __builtin_amdgcn_sched_barrier(0);
  }
  asm volatile("s_waitcnt vmcnt(0)" ::: "memory");
  __builtin_amdgcn_s_barrier();
  __builtin_amdgcn_sched_barrier(0);
  compute_tile<true>(lds + ((nt - 1) & 1) * 16384, qf0, qf1, (nt - 1) * 64, qrow,
                     lg, ln, m2, l_run, o);
  __builtin_amdgcn_s_barrier();
  __builtin_amdgcn_sched_barrier(0);

  const float inv = 1.0f / l_run;
  const int bb = bh >> 4, hh = bh & 15;
  const size_t orow = (size_t)(bb * SEQ + qrow) * HID + hh * HD;
#pragma unroll
  for (int mt = 0; mt < 4; mt++) {
    s16x4 ov;
#pragma unroll
    for (int r = 0; r < 4; r++) ov[r] = f2bf(o[mt][r] * inv);
    *(s16x4*)(Ob + orow + mt * 16 + lg * 4) = ov;
  }
}

__global__ __launch_bounds__(256) void attn_kernel(const short* __restrict__ Qb,
                                                   const short* __restrict__ Kg,
                                                   const short* __restrict__ Vg,
                                                   short* __restrict__ Ob) {
  __shared__ char lds[32768];  // 2 buffers x (8KB K + 8KB V)
  // XCD swizzle: 512 blocks, 8 XCDs -> XCD k owns 64 consecutive logical blocks
  // (4 heads) so each XCD's L2 holds a 2MB K/V working set.
  const int bid = blockIdx.x;
  const int L = (bid & 7) * 64 + (bid >> 3);
  const int bh = L >> 4, g = L & 15;
  const int w = threadIdx.x >> 6, l = threadIdx.x & 63;
  const short* Kt = Kg + (size_t)bh * (SEQ * HD);
  const short* Vt = Vg + (size_t)bh * (SEQ * HD);
  attn_group_pass(Kt, Vt, Qb, Ob, bh, g, w, l, lds);       // short pass (g+1 tiles)
  attn_group_pass(Kt, Vt, Qb, Ob, bh, 31 - g, w, l, lds);  // long pass (32-g tiles)
}

// ---------------- launch ----------------
extern "C" void kernel_launch(void* const* d_in, const int* in_sizes, int n_in,
                              void* d_out, int out_size, void* d_ws,
                              size_t ws_size, hipStream_t stream) {
  const float* X = (const float*)d_in[0];
  // d_in[1] = mask (causal, implemented directly)
  const float* Wq = (const float*)d_in[2];
  const float* bq = (const float*)d_in[3];
  const float* Wk = (const float*)d_in[4];
  const float* bk = (const float*)d_in[5];
  const float* Wv = (const float*)d_in[6];
  const float* bv = (const float*)d_in[7];
  const float* Wo = (const float*)d_in[8];
  const float* bo = (const float*)d_in[9];
  float* out = (float*)d_out;

  char* ws = (char*)d_ws;
  short* Xb = (short*)(ws);                  // 8 MB  [4096][1024]
  short* Wtall = (short*)(ws + (8u << 20));  // 8 MB  (Wq|Wk|Wv|Wo)^T bf16
  short* Qb = (short*)(ws + (16u << 20));    // 8 MB  [32][2048][64]
  short* Kg = (short*)(ws + (24u << 20));    // 8 MB  [32][32 tiles][64x64 image]
  short* Vg = (short*)(ws + (32u << 20));    // 8 MB  [32][32 tiles][64x64 image]
  short* Ob = (short*)(ws + (40u << 20));    // 8 MB  [4096][1024]
  short* Wto = Wtall + (3u << 20);

  cast_x_kernel<<<2048, 256, 0, stream>>>(X, Xb);
  transpose_cast4_kernel<<<dim3(32, 32, 4), 256, 0, stream>>>(Wq, Wk, Wv, Wo,
                                                              Wtall);

  gemm_bf16<0><<<dim3(24, 32), 256, 0, stream>>>(Xb, Wtall, bq, bk, bv, Qb, Kg,
                                                 Vg, nullptr);
  attn_kernel<<<512, 256, 0, stream>>>(Qb, Kg, Vg, Ob);
  gemm_bf16<1><<<dim3(8, 32), 256, 0, stream>>>(Ob, Wto, bo, nullptr, nullptr,
                                                nullptr, nullptr, nullptr, out);
}

// Round 7
// 226.958 us; speedup vs baseline: 1.3059x; 1.0485x over previous
//
#include <hip/hip_runtime.h>
#include <stdint.h>

#define HID 1024
#define SEQ 2048
#define NB 2
#define NH 16
#define HD 64
#define MROWS 4096  // NB*SEQ

typedef float f32x4 __attribute__((ext_vector_type(4)));
typedef short s16x4 __attribute__((ext_vector_type(4)));
typedef short s16x8 __attribute__((ext_vector_type(8)));
typedef uint32_t u32x4 __attribute__((ext_vector_type(4)));

#define MFMA16(a, b, c) __builtin_amdgcn_mfma_f32_16x16x32_bf16((a), (b), (c), 0, 0, 0)

#define GLOAD_LDS16(gp, lp)                                                    \
  __builtin_amdgcn_global_load_lds(                                            \
      (const __attribute__((address_space(1))) unsigned int*)(gp),             \
      (__attribute__((address_space(3))) unsigned int*)(lp), 16, 0, 0)

__device__ __forceinline__ short f2bf(float x) {
  uint32_t u = __builtin_bit_cast(uint32_t, x);
  u += 0x7fffu + ((u >> 16) & 1u);
  return (short)(u >> 16);
}

__device__ __forceinline__ uint32_t cvtpk(float lo, float hi) {
  uint32_t r;
  asm("v_cvt_pk_bf16_f32 %0, %1, %2" : "=v"(r) : "v"(lo), "v"(hi));
  return r;
}

// -------- merged prep: z<4 -> transpose-cast W_z; z==4 -> cast X --------
__global__ __launch_bounds__(256) void prep_kernel(
    const float* __restrict__ X, const float* __restrict__ w0,
    const float* __restrict__ w1, const float* __restrict__ w2,
    const float* __restrict__ w3, short* __restrict__ Xb,
    short* __restrict__ Wtall) {
  const int z = blockIdx.z;
  if (z == 4) {  // cast X: 1024 blocks x 16 elems/thread
    const size_t i = ((size_t)blockIdx.y * 32 + blockIdx.x) * 256 + threadIdx.x;
    const float* s = X + i * 16;
    short* d = Xb + i * 16;
#pragma unroll
    for (int h = 0; h < 2; h++) {
      f32x4 a = *(const f32x4*)(s + h * 8);
      f32x4 b = *(const f32x4*)(s + h * 8 + 4);
      s16x8 o;
      o[0] = f2bf(a[0]); o[1] = f2bf(a[1]); o[2] = f2bf(a[2]); o[3] = f2bf(a[3]);
      o[4] = f2bf(b[0]); o[5] = f2bf(b[1]); o[6] = f2bf(b[2]); o[7] = f2bf(b[3]);
      *(s16x8*)(d + h * 8) = o;
    }
    return;
  }
  __shared__ float t[32][33];
  const float* src = (z == 0) ? w0 : (z == 1) ? w1 : (z == 2) ? w2 : w3;
  short* dst = Wtall + ((size_t)z << 20);
  const int tx = threadIdx.x & 31, ty = threadIdx.x >> 5;
  const int r0 = blockIdx.y * 32, c0 = blockIdx.x * 32;
#pragma unroll
  for (int i = 0; i < 4; i++)
    t[ty + i * 8][tx] = src[(size_t)(r0 + ty + i * 8) * HID + c0 + tx];
  __syncthreads();
#pragma unroll
  for (int i = 0; i < 4; i++)
    dst[(size_t)(c0 + ty + i * 8) * HID + r0 + tx] = f2bf(t[tx][ty + i * 8]);
}

// ---------------- bf16 GEMM: C = A[M][1024] * Bt[N][1024]^T ----------------
// Tile (32*MI)x128, BK=32, 4 waves (2x2), 16x16x32 MFMA, global_load_lds.
// EPI 0 (MI=4): QKV epilogue: bias + scatter; Q pre-scaled by 0.125*log2(e).
//   Q -> Qb [bh][s][d] * SC
//   K -> Kg [bh][tile][64x64 image]: off = r*64 + ((d/8 ^ (r&7))*8) + d%8
//   V -> Vg [bh][tile][64x64 image]: kappa slot kp; off = d*64 + ((kp/8^(d&7))*8)+kp%7==... see code
// EPI 1: proj epilogue (bias + f32 out [m][1024])
template <int EPI, int MI>
__global__ __launch_bounds__(256) void gemm_bf16(
    const short* __restrict__ A, const short* __restrict__ Bt,
    const float* __restrict__ b0, const float* __restrict__ b1,
    const float* __restrict__ b2, short* __restrict__ Qb, short* __restrict__ Kg,
    short* __restrict__ Vg, float* __restrict__ Out) {
  __shared__ char lds[MI * 2048 + 8192];  // A tile [32*MI][32], B tile [128][32]
  const int tid = threadIdx.x;
  const int w = tid >> 6, l = tid & 63, lg = l >> 4, ln = l & 15;
  const int wm = w >> 1, wn = w & 1;
  const int m0 = blockIdx.y * (32 * MI), n0 = blockIdx.x * 128;

  f32x4 acc[MI][4];
#pragma unroll
  for (int i = 0; i < MI; i++)
#pragma unroll
    for (int j = 0; j < 4; j++) acc[i][j] = f32x4{0.f, 0.f, 0.f, 0.f};

  for (int k0 = 0; k0 < 1024; k0 += 32) {
    __syncthreads();  // protect LDS from prior-iter readers
#pragma unroll
    for (int i = 0; i < MI / 2; i++) {  // A: MI*128 16B-chunks
      const int c = i * 256 + tid;
      const int row = c >> 2;
      const int cs = (c & 3) ^ (row & 3);  // source-side XOR swizzle
      GLOAD_LDS16(A + (size_t)(m0 + row) * 1024 + k0 + cs * 8, lds + c * 16);
    }
#pragma unroll
    for (int i = 0; i < 2; i++) {  // B: 512 chunks
      const int c = i * 256 + tid;
      const int row = c >> 2;
      const int cs = (c & 3) ^ (row & 3);
      GLOAD_LDS16(Bt + (size_t)(n0 + row) * 1024 + k0 + cs * 8,
                  lds + MI * 2048 + c * 16);
    }
    __syncthreads();  // compiler emits vmcnt(0) before barrier

    s16x8 af[MI], bfr[4];
#pragma unroll
    for (int mi = 0; mi < MI; mi++) {
      const int row = wm * (16 * MI) + mi * 16 + ln;
      af[mi] = *(const s16x8*)(lds + row * 64 + ((lg ^ (row & 3)) * 16));
    }
#pragma unroll
    for (int ni = 0; ni < 4; ni++) {
      const int row = wn * 64 + ni * 16 + ln;
      bfr[ni] =
          *(const s16x8*)(lds + MI * 2048 + row * 64 + ((lg ^ (row & 3)) * 16));
    }
#pragma unroll
    for (int mi = 0; mi < MI; mi++)
#pragma unroll
      for (int ni = 0; ni < 4; ni++)
        acc[mi][ni] = MFMA16(af[mi], bfr[ni], acc[mi][ni]);
  }

  // epilogue: C/D layout row=(lane>>4)*4+reg, col=lane&15
  const float QSC = 0.18033688011112042f;  // (1/8) * log2(e)
#pragma unroll
  for (int ni = 0; ni < 4; ni++) {
    const int c = n0 + wn * 64 + ni * 16 + ln;
    if (EPI == 0) {
      const int mat = c >> 10, cc = c & 1023, hh = cc >> 6, d = cc & 63;
      const float* bp = (mat == 0) ? b0 : (mat == 1) ? b1 : b2;
      const float bias = bp[cc];
#pragma unroll
      for (int mi = 0; mi < MI; mi++) {
#pragma unroll
        for (int r = 0; r < 4; r++) {
          const int m = m0 + wm * (16 * MI) + mi * 16 + lg * 4 + r;
          const int bb = m >> 11, s = m & 2047;
          const float fv = acc[mi][ni][r] + bias;
          const size_t bh = (size_t)(bb * 16 + hh);
          if (mat == 0) {
            Qb[(bh * SEQ + s) * HD + d] = f2bf(fv * QSC);  // pre-scaled Q
          } else if (mat == 1) {
            const int tile = s >> 6, rr = s & 63;
            Kg[bh * (SEQ * HD) + tile * 4096 + rr * 64 +
               ((((d >> 3) ^ (rr & 7)) << 3) | (d & 7))] = f2bf(fv);
          } else {
            // kappa-permute s within its 32-group (PV frag key order):
            const int sp = (s & ~31) | ((s & 12) << 1) | (((s >> 4) & 1) << 2) |
                           (s & 3);
            const int tile = sp >> 6, kp = sp & 63;
            Vg[bh * (SEQ * HD) + tile * 4096 + d * 64 +
               ((((kp >> 3) ^ (d & 7)) << 3) | (kp & 7))] = f2bf(fv);
          }
        }
      }
    } else {
      const float bias = b0[c];
#pragma unroll
      for (int mi = 0; mi < MI; mi++)
#pragma unroll
        for (int r = 0; r < 4; r++) {
          const int m = m0 + wm * (16 * MI) + mi * 16 + lg * 4 + r;
          Out[(size_t)m * 1024 + c] = acc[mi][ni][r] + bias;
        }
    }
  }
}

// ------------- flash attention (causal), block-cooperative LDS pipeline -------------
// 512 blocks (XCD-swizzled), 4 waves/block, 64-row Q group, double-buffered
// K/V LDS staging via global_load_lds + counted vmcnt. Causal pairing (g,31-g).
// VALU diet: Q pre-scaled (exp2-domain direct), defer-max (THR=8), psum via
// ones-MFMA (no cross-lane shuffles), v_cvt_pk_bf16_f32 P-packing.

__device__ __forceinline__ void stage_tile(const short* Kt, const short* Vt,
                                           int t, char* buf, int w, int l) {
  const char* src = (w < 2) ? ((const char*)(Kt + (size_t)t * 4096) + (w & 1) * 4096)
                            : ((const char*)(Vt + (size_t)t * 4096) + (w & 1) * 4096);
  char* dst = buf + ((w < 2) ? 0 : 8192) + (w & 1) * 4096;
#pragma unroll
  for (int j = 0; j < 4; j++)
    GLOAD_LDS16(src + j * 1024 + l * 16, dst + j * 1024);
}

template <bool MASK>
__device__ __forceinline__ void softmax_pv(f32x4 st[4], const s16x8 vf[2][4],
                                           const s16x8& ones, f32x4 o[4],
                                           float& m2, float& l_run, int k0,
                                           int qrow, int lg) {
  float p[4][4];
#pragma unroll
  for (int mt = 0; mt < 4; mt++)
#pragma unroll
    for (int r = 0; r < 4; r++) {
      float v = st[mt][r];  // already in exp2 domain (Q pre-scaled)
      if (MASK) {
        const int key = k0 + mt * 16 + lg * 4 + r;
        if (key > qrow) v = -3e38f;
      }
      p[mt][r] = v;
    }
  // per-lane max tree (max3-friendly)
  float a0 = fmaxf(fmaxf(p[0][0], p[0][1]), fmaxf(p[0][2], p[0][3]));
  float a1 = fmaxf(fmaxf(p[1][0], p[1][1]), fmaxf(p[1][2], p[1][3]));
  float a2 = fmaxf(fmaxf(p[2][0], p[2][1]), fmaxf(p[2][2], p[2][3]));
  float a3 = fmaxf(fmaxf(p[3][0], p[3][1]), fmaxf(p[3][2], p[3][3]));
  float pmax = fmaxf(fmaxf(a0, a1), fmaxf(a2, a3));

  if (!__all(pmax <= m2 + 8.0f)) {  // defer-max: rescale only on real growth
    pmax = fmaxf(pmax, __shfl_xor(pmax, 16));
    pmax = fmaxf(pmax, __shfl_xor(pmax, 32));
    const float m_new = fmaxf(m2, pmax);
    const float corr = exp2f(m2 - m_new);
    l_run *= corr;
#pragma unroll
    for (int i = 0; i < 4; i++) o[i] *= corr;
    m2 = m_new;
  }
#pragma unroll
  for (int mt = 0; mt < 4; mt++)
#pragma unroll
    for (int r = 0; r < 4; r++) p[mt][r] = exp2f(p[mt][r] - m2);

  s16x8 pf[2];
#pragma unroll
  for (int s = 0; s < 2; s++) {
    u32x4 wv;
    wv[0] = cvtpk(p[s * 2][0], p[s * 2][1]);
    wv[1] = cvtpk(p[s * 2][2], p[s * 2][3]);
    wv[2] = cvtpk(p[s * 2 + 1][0], p[s * 2 + 1][1]);
    wv[3] = cvtpk(p[s * 2 + 1][2], p[s * 2 + 1][3]);
    pf[s] = __builtin_bit_cast(s16x8, wv);
  }
  // psum via ones-MFMA: D[i][q] = sum_k P[k][q], replicated across rows
  f32x4 ps = f32x4{0.f, 0.f, 0.f, 0.f};
  ps = MFMA16(ones, pf[0], ps);
  ps = MFMA16(ones, pf[1], ps);
#pragma unroll
  for (int s = 0; s < 2; s++)
#pragma unroll
    for (int vmt = 0; vmt < 4; vmt++)
      o[vmt] = MFMA16(vf[s][vmt], pf[s], o[vmt]);
  l_run += ps[0];
}

template <bool MASK>
__device__ __forceinline__ void compute_tile(const char* cbuf, const s16x8& qf0,
                                             const s16x8& qf1, const s16x8& ones,
                                             int k0, int qrow, int lg, int ln,
                                             float& m2, float& l_run, f32x4 o[4]) {
  const int x = ln & 7;
  f32x4 st[4];
#pragma unroll
  for (int mt = 0; mt < 4; mt++) {
    const char* rowp = cbuf + (mt * 16 + ln) * 128;
    const s16x8 k0f = *(const s16x8*)(rowp + ((lg ^ x) * 16));
    const s16x8 k1f = *(const s16x8*)(rowp + (((4 + lg) ^ x) * 16));
    st[mt] = f32x4{0.f, 0.f, 0.f, 0.f};
    st[mt] = MFMA16(k0f, qf0, st[mt]);
    st[mt] = MFMA16(k1f, qf1, st[mt]);
  }
  s16x8 vf[2][4];
#pragma unroll
  for (int s = 0; s < 2; s++)
#pragma unroll
    for (int vmt = 0; vmt < 4; vmt++)
      vf[s][vmt] = *(const s16x8*)(cbuf + 8192 + (vmt * 16 + ln) * 128 +
                                   (((s * 4 + lg) ^ x) * 16));
  softmax_pv<MASK>(st, vf, ones, o, m2, l_run, k0, qrow, lg);
}

__device__ __forceinline__ void attn_group_pass(const short* Kt, const short* Vt,
                                                const short* __restrict__ Qb,
                                                short* __restrict__ Ob, int bh,
                                                int G, int w, int l, char* lds) {
  const int lg = l >> 4, ln = l & 15;
  const int qrow = G * 64 + w * 16 + ln;
  const short* Qp = Qb + ((size_t)bh * SEQ + qrow) * HD;
  const s16x8 qf0 = *(const s16x8*)(Qp + lg * 8);
  const s16x8 qf1 = *(const s16x8*)(Qp + 32 + lg * 8);
  s16x8 ones;
#pragma unroll
  for (int j = 0; j < 8; j++) ones[j] = (short)0x3F80;  // bf16 1.0

  float m2 = -3e38f, l_run = 0.f;
  f32x4 o[4];
#pragma unroll
  for (int i = 0; i < 4; i++) o[i] = f32x4{0.f, 0.f, 0.f, 0.f};

  const int nt = G + 1;  // tiles 0..G; tile G is the masked diagonal
  stage_tile(Kt, Vt, 0, lds, w, l);
  for (int t = 0; t < nt - 1; ++t) {
    stage_tile(Kt, Vt, t + 1, lds + ((t + 1) & 1) * 16384, w, l);
    asm volatile("s_waitcnt vmcnt(4)" ::: "memory");  // tile t resident
    __builtin_amdgcn_s_barrier();
    __builtin_amdgcn_sched_barrier(0);
    compute_tile<false>(lds + (t & 1) * 16384, qf0, qf1, ones, t * 64, qrow, lg,
                        ln, m2, l_run, o);
    __builtin_amdgcn_s_barrier();  // all waves done reading before overwrite
    __builtin_amdgcn_sched_barrier(0);
  }
  asm volatile("s_waitcnt vmcnt(0)" ::: "memory");
  __builtin_amdgcn_s_barrier();
  __builtin_amdgcn_sched_barrier(0);
  compute_tile<true>(lds + ((nt - 1) & 1) * 16384, qf0, qf1, ones, (nt - 1) * 64,
                     qrow, lg, ln, m2, l_run, o);
  __builtin_amdgcn_s_barrier();
  __builtin_amdgcn_sched_barrier(0);

  const float inv = 1.0f / l_run;
  const int bb = bh >> 4, hh = bh & 15;
  const size_t orow = (size_t)(bb * SEQ + qrow) * HID + hh * HD;
#pragma unroll
  for (int mt = 0; mt < 4; mt++) {
    s16x4 ov;
#pragma unroll
    for (int r = 0; r < 4; r++) ov[r] = f2bf(o[mt][r] * inv);
    *(s16x4*)(Ob + orow + mt * 16 + lg * 4) = ov;
  }
}

__global__ __launch_bounds__(256) void attn_kernel(const short* __restrict__ Qb,
                                                   const short* __restrict__ Kg,
                                                   const short* __restrict__ Vg,
                                                   short* __restrict__ Ob) {
  __shared__ char lds[32768];  // 2 buffers x (8KB K + 8KB V)
  // XCD swizzle: XCD k owns 64 consecutive logical blocks (4 heads).
  const int bid = blockIdx.x;
  const int L = (bid & 7) * 64 + (bid >> 3);
  const int bh = L >> 4, g = L & 15;
  const int w = threadIdx.x >> 6, l = threadIdx.x & 63;
  const short* Kt = Kg + (size_t)bh * (SEQ * HD);
  const short* Vt = Vg + (size_t)bh * (SEQ * HD);
  attn_group_pass(Kt, Vt, Qb, Ob, bh, g, w, l, lds);       // short pass
  attn_group_pass(Kt, Vt, Qb, Ob, bh, 31 - g, w, l, lds);  // long pass
}

// ---------------- launch ----------------
extern "C" void kernel_launch(void* const* d_in, const int* in_sizes, int n_in,
                              void* d_out, int out_size, void* d_ws,
                              size_t ws_size, hipStream_t stream) {
  const float* X = (const float*)d_in[0];
  // d_in[1] = mask (causal, implemented directly)
  const float* Wq = (const float*)d_in[2];
  const float* bq = (const float*)d_in[3];
  const float* Wk = (const float*)d_in[4];
  const float* bk = (const float*)d_in[5];
  const float* Wv = (const float*)d_in[6];
  const float* bv = (const float*)d_in[7];
  const float* Wo = (const float*)d_in[8];
  const float* bo = (const float*)d_in[9];
  float* out = (float*)d_out;

  char* ws = (char*)d_ws;
  short* Xb = (short*)(ws);                  // 8 MB  [4096][1024]
  short* Wtall = (short*)(ws + (8u << 20));  // 8 MB  (Wq|Wk|Wv|Wo)^T bf16
  short* Qb = (short*)(ws + (16u << 20));    // 8 MB  [32][2048][64] (pre-scaled)
  short* Kg = (short*)(ws + (24u << 20));    // 8 MB  [32][32 tiles][64x64 image]
  short* Vg = (short*)(ws + (32u << 20));    // 8 MB  [32][32 tiles][64x64 image]
  short* Ob = (short*)(ws + (40u << 20));    // 8 MB  [4096][1024]
  short* Wto = Wtall + (3u << 20);

  prep_kernel<<<dim3(32, 32, 5), 256, 0, stream>>>(X, Wq, Wk, Wv, Wo, Xb, Wtall);

  gemm_bf16<0, 4><<<dim3(24, 32), 256, 0, stream>>>(Xb, Wtall, bq, bk, bv, Qb,
                                                    Kg, Vg, nullptr);
  attn_kernel<<<512, 256, 0, stream>>>(Qb, Kg, Vg, Ob);
  gemm_bf16<1, 2><<<dim3(8, 64), 256, 0, stream>>>(Ob, Wto, bo, nullptr, nullptr,
                                                   nullptr, nullptr, nullptr,
                                                   out);
}

// Round 8
// 212.590 us; speedup vs baseline: 1.3942x; 1.0676x over previous
//
#include <hip/hip_runtime.h>
#include <stdint.h>

#define HID 1024
#define SEQ 2048
#define NB 2
#define NH 16
#define HD 64
#define MROWS 4096  // NB*SEQ

typedef float f32x4 __attribute__((ext_vector_type(4)));
typedef short s16x4 __attribute__((ext_vector_type(4)));
typedef short s16x8 __attribute__((ext_vector_type(8)));
typedef uint32_t u32x4 __attribute__((ext_vector_type(4)));

#define MFMA16(a, b, c) __builtin_amdgcn_mfma_f32_16x16x32_bf16((a), (b), (c), 0, 0, 0)

#define GLOAD_LDS16(gp, lp)                                                    \
  __builtin_amdgcn_global_load_lds(                                            \
      (const __attribute__((address_space(1))) unsigned int*)(gp),             \
      (__attribute__((address_space(3))) unsigned int*)(lp), 16, 0, 0)

__device__ __forceinline__ short f2bf(float x) {
  uint32_t u = __builtin_bit_cast(uint32_t, x);
  u += 0x7fffu + ((u >> 16) & 1u);
  return (short)(u >> 16);
}

__device__ __forceinline__ uint32_t cvtpk(float lo, float hi) {
  uint32_t r;
  asm("v_cvt_pk_bf16_f32 %0, %1, %2" : "=v"(r) : "v"(lo), "v"(hi));
  return r;
}

// -------- merged prep: z<4 -> transpose-cast W_z; z==4 -> cast X --------
__global__ __launch_bounds__(256) void prep_kernel(
    const float* __restrict__ X, const float* __restrict__ w0,
    const float* __restrict__ w1, const float* __restrict__ w2,
    const float* __restrict__ w3, short* __restrict__ Xb,
    short* __restrict__ Wtall) {
  const int z = blockIdx.z;
  if (z == 4) {  // cast X: 1024 blocks x 16 elems/thread
    const size_t i = ((size_t)blockIdx.y * 32 + blockIdx.x) * 256 + threadIdx.x;
    const float* s = X + i * 16;
    short* d = Xb + i * 16;
#pragma unroll
    for (int h = 0; h < 2; h++) {
      f32x4 a = *(const f32x4*)(s + h * 8);
      f32x4 b = *(const f32x4*)(s + h * 8 + 4);
      s16x8 o;
      o[0] = f2bf(a[0]); o[1] = f2bf(a[1]); o[2] = f2bf(a[2]); o[3] = f2bf(a[3]);
      o[4] = f2bf(b[0]); o[5] = f2bf(b[1]); o[6] = f2bf(b[2]); o[7] = f2bf(b[3]);
      *(s16x8*)(d + h * 8) = o;
    }
    return;
  }
  __shared__ float t[32][33];
  const float* src = (z == 0) ? w0 : (z == 1) ? w1 : (z == 2) ? w2 : w3;
  short* dst = Wtall + ((size_t)z << 20);
  const int tx = threadIdx.x & 31, ty = threadIdx.x >> 5;
  const int r0 = blockIdx.y * 32, c0 = blockIdx.x * 32;
#pragma unroll
  for (int i = 0; i < 4; i++)
    t[ty + i * 8][tx] = src[(size_t)(r0 + ty + i * 8) * HID + c0 + tx];
  __syncthreads();
#pragma unroll
  for (int i = 0; i < 4; i++)
    dst[(size_t)(c0 + ty + i * 8) * HID + r0 + tx] = f2bf(t[tx][ty + i * 8]);
}

// ---------------- bf16 GEMM: C = A[M][1024] * Bt[N][1024]^T ----------------
// Tile (32*MI)x128, BK=32, 4 waves (2x2), 16x16x32 MFMA.
// Double-buffered LDS via global_load_lds + counted vmcnt (attn-proven
// pipeline): stage(next) -> vmcnt(NLD) -> barrier -> compute(cur) -> barrier.
// EPI 0 (MI=4): QKV epilogue: bias + scatter; Q pre-scaled by 0.125*log2(e).
// EPI 1: proj epilogue (bias + f32 out [m][1024])
template <int EPI, int MI>
__global__ __launch_bounds__(256) void gemm_bf16(
    const short* __restrict__ A, const short* __restrict__ Bt,
    const float* __restrict__ b0, const float* __restrict__ b1,
    const float* __restrict__ b2, short* __restrict__ Qb, short* __restrict__ Kg,
    short* __restrict__ Vg, float* __restrict__ Out) {
  __shared__ char lds[2][MI * 2048 + 8192];  // dbuf x (A [32*MI][32], B [128][32])
  const int tid = threadIdx.x;
  const int w = tid >> 6, l = tid & 63, lg = l >> 4, ln = l & 15;
  const int wm = w >> 1, wn = w & 1;
  const int m0 = blockIdx.y * (32 * MI), n0 = blockIdx.x * 128;

  f32x4 acc[MI][4];
#pragma unroll
  for (int i = 0; i < MI; i++)
#pragma unroll
    for (int j = 0; j < 4; j++) acc[i][j] = f32x4{0.f, 0.f, 0.f, 0.f};

  auto stage = [&](int buf, int k0) {
#pragma unroll
    for (int i = 0; i < MI / 2; i++) {  // A: MI*128 16B-chunks
      const int c = i * 256 + tid;
      const int row = c >> 2;
      const int cs = (c & 3) ^ (row & 3);  // source-side XOR swizzle
      GLOAD_LDS16(A + (size_t)(m0 + row) * 1024 + k0 + cs * 8,
                  lds[buf] + c * 16);
    }
#pragma unroll
    for (int i = 0; i < 2; i++) {  // B: 512 chunks
      const int c = i * 256 + tid;
      const int row = c >> 2;
      const int cs = (c & 3) ^ (row & 3);
      GLOAD_LDS16(Bt + (size_t)(n0 + row) * 1024 + k0 + cs * 8,
                  lds[buf] + MI * 2048 + c * 16);
    }
  };

  stage(0, 0);
  for (int kt = 0; kt < 32; ++kt) {
    const int cur = kt & 1;
    if (kt < 31) {
      stage(cur ^ 1, (kt + 1) * 32);  // next tile's loads stay in flight
      if constexpr (MI == 4)
        asm volatile("s_waitcnt vmcnt(4)" ::: "memory");
      else
        asm volatile("s_waitcnt vmcnt(3)" ::: "memory");
    } else {
      asm volatile("s_waitcnt vmcnt(0)" ::: "memory");
    }
    __builtin_amdgcn_s_barrier();  // cur tile resident for all waves
    __builtin_amdgcn_sched_barrier(0);

    const char* ldsc = lds[cur];
    s16x8 af[MI], bfr[4];
#pragma unroll
    for (int mi = 0; mi < MI; mi++) {
      const int row = wm * (16 * MI) + mi * 16 + ln;
      af[mi] = *(const s16x8*)(ldsc + row * 64 + ((lg ^ (row & 3)) * 16));
    }
#pragma unroll
    for (int ni = 0; ni < 4; ni++) {
      const int row = wn * 64 + ni * 16 + ln;
      bfr[ni] =
          *(const s16x8*)(ldsc + MI * 2048 + row * 64 + ((lg ^ (row & 3)) * 16));
    }
#pragma unroll
    for (int mi = 0; mi < MI; mi++)
#pragma unroll
      for (int ni = 0; ni < 4; ni++)
        acc[mi][ni] = MFMA16(af[mi], bfr[ni], acc[mi][ni]);

    __builtin_amdgcn_s_barrier();  // all reads done before next overwrite
    __builtin_amdgcn_sched_barrier(0);
  }

  // epilogue: C/D layout row=(lane>>4)*4+reg, col=lane&15
  const float QSC = 0.18033688011112042f;  // (1/8) * log2(e)
#pragma unroll
  for (int ni = 0; ni < 4; ni++) {
    const int c = n0 + wn * 64 + ni * 16 + ln;
    if (EPI == 0) {
      const int mat = c >> 10, cc = c & 1023, hh = cc >> 6, d = cc & 63;
      const float* bp = (mat == 0) ? b0 : (mat == 1) ? b1 : b2;
      const float bias = bp[cc];
#pragma unroll
      for (int mi = 0; mi < MI; mi++) {
#pragma unroll
        for (int r = 0; r < 4; r++) {
          const int m = m0 + wm * (16 * MI) + mi * 16 + lg * 4 + r;
          const int bb = m >> 11, s = m & 2047;
          const float fv = acc[mi][ni][r] + bias;
          const size_t bh = (size_t)(bb * 16 + hh);
          if (mat == 0) {
            Qb[(bh * SEQ + s) * HD + d] = f2bf(fv * QSC);  // pre-scaled Q
          } else if (mat == 1) {
            const int tile = s >> 6, rr = s & 63;
            Kg[bh * (SEQ * HD) + tile * 4096 + rr * 64 +
               ((((d >> 3) ^ (rr & 7)) << 3) | (d & 7))] = f2bf(fv);
          } else {
            // kappa-permute s within its 32-group (PV frag key order):
            const int sp = (s & ~31) | ((s & 12) << 1) | (((s >> 4) & 1) << 2) |
                           (s & 3);
            const int tile = sp >> 6, kp = sp & 63;
            Vg[bh * (SEQ * HD) + tile * 4096 + d * 64 +
               ((((kp >> 3) ^ (d & 7)) << 3) | (kp & 7))] = f2bf(fv);
          }
        }
      }
    } else {
      const float bias = b0[c];
#pragma unroll
      for (int mi = 0; mi < MI; mi++)
#pragma unroll
        for (int r = 0; r < 4; r++) {
          const int m = m0 + wm * (16 * MI) + mi * 16 + lg * 4 + r;
          Out[(size_t)m * 1024 + c] = acc[mi][ni][r] + bias;
        }
    }
  }
}

// ------------- flash attention (causal), block-cooperative LDS pipeline -------------
// 512 blocks (XCD-swizzled), 4 waves/block, 64-row Q group, double-buffered
// K/V LDS staging via global_load_lds + counted vmcnt. Causal pairing (g,31-g).
// VALU diet: Q pre-scaled (exp2-domain direct), defer-max (THR=8), psum via
// ones-MFMA (no cross-lane shuffles), v_cvt_pk_bf16_f32 P-packing.

__device__ __forceinline__ void stage_tile(const short* Kt, const short* Vt,
                                           int t, char* buf, int w, int l) {
  const char* src = (w < 2) ? ((const char*)(Kt + (size_t)t * 4096) + (w & 1) * 4096)
                            : ((const char*)(Vt + (size_t)t * 4096) + (w & 1) * 4096);
  char* dst = buf + ((w < 2) ? 0 : 8192) + (w & 1) * 4096;
#pragma unroll
  for (int j = 0; j < 4; j++)
    GLOAD_LDS16(src + j * 1024 + l * 16, dst + j * 1024);
}

template <bool MASK>
__device__ __forceinline__ void softmax_pv(f32x4 st[4], const s16x8 vf[2][4],
                                           const s16x8& ones, f32x4 o[4],
                                           float& m2, float& l_run, int k0,
                                           int qrow, int lg) {
  float p[4][4];
#pragma unroll
  for (int mt = 0; mt < 4; mt++)
#pragma unroll
    for (int r = 0; r < 4; r++) {
      float v = st[mt][r];  // already in exp2 domain (Q pre-scaled)
      if (MASK) {
        const int key = k0 + mt * 16 + lg * 4 + r;
        if (key > qrow) v = -3e38f;
      }
      p[mt][r] = v;
    }
  // per-lane max tree
  float a0 = fmaxf(fmaxf(p[0][0], p[0][1]), fmaxf(p[0][2], p[0][3]));
  float a1 = fmaxf(fmaxf(p[1][0], p[1][1]), fmaxf(p[1][2], p[1][3]));
  float a2 = fmaxf(fmaxf(p[2][0], p[2][1]), fmaxf(p[2][2], p[2][3]));
  float a3 = fmaxf(fmaxf(p[3][0], p[3][1]), fmaxf(p[3][2], p[3][3]));
  float pmax = fmaxf(fmaxf(a0, a1), fmaxf(a2, a3));

  if (!__all(pmax <= m2 + 8.0f)) {  // defer-max: rescale only on real growth
    pmax = fmaxf(pmax, __shfl_xor(pmax, 16));
    pmax = fmaxf(pmax, __shfl_xor(pmax, 32));
    const float m_new = fmaxf(m2, pmax);
    const float corr = exp2f(m2 - m_new);
    l_run *= corr;
#pragma unroll
    for (int i = 0; i < 4; i++) o[i] *= corr;
    m2 = m_new;
  }
#pragma unroll
  for (int mt = 0; mt < 4; mt++)
#pragma unroll
    for (int r = 0; r < 4; r++) p[mt][r] = exp2f(p[mt][r] - m2);

  s16x8 pf[2];
#pragma unroll
  for (int s = 0; s < 2; s++) {
    u32x4 wv;
    wv[0] = cvtpk(p[s * 2][0], p[s * 2][1]);
    wv[1] = cvtpk(p[s * 2][2], p[s * 2][3]);
    wv[2] = cvtpk(p[s * 2 + 1][0], p[s * 2 + 1][1]);
    wv[3] = cvtpk(p[s * 2 + 1][2], p[s * 2 + 1][3]);
    pf[s] = __builtin_bit_cast(s16x8, wv);
  }
  // psum via ones-MFMA: D[i][q] = sum_k P[k][q], replicated across rows
  f32x4 ps = f32x4{0.f, 0.f, 0.f, 0.f};
  ps = MFMA16(ones, pf[0], ps);
  ps = MFMA16(ones, pf[1], ps);
#pragma unroll
  for (int s = 0; s < 2; s++)
#pragma unroll
    for (int vmt = 0; vmt < 4; vmt++)
      o[vmt] = MFMA16(vf[s][vmt], pf[s], o[vmt]);
  l_run += ps[0];
}

template <bool MASK>
__device__ __forceinline__ void compute_tile(const char* cbuf, const s16x8& qf0,
                                             const s16x8& qf1, const s16x8& ones,
                                             int k0, int qrow, int lg, int ln,
                                             float& m2, float& l_run, f32x4 o[4]) {
  const int x = ln & 7;
  f32x4 st[4];
#pragma unroll
  for (int mt = 0; mt < 4; mt++) {
    const char* rowp = cbuf + (mt * 16 + ln) * 128;
    const s16x8 k0f = *(const s16x8*)(rowp + ((lg ^ x) * 16));
    const s16x8 k1f = *(const s16x8*)(rowp + (((4 + lg) ^ x) * 16));
    st[mt] = f32x4{0.f, 0.f, 0.f, 0.f};
    st[mt] = MFMA16(k0f, qf0, st[mt]);
    st[mt] = MFMA16(k1f, qf1, st[mt]);
  }
  s16x8 vf[2][4];
#pragma unroll
  for (int s = 0; s < 2; s++)
#pragma unroll
    for (int vmt = 0; vmt < 4; vmt++)
      vf[s][vmt] = *(const s16x8*)(cbuf + 8192 + (vmt * 16 + ln) * 128 +
                                   (((s * 4 + lg) ^ x) * 16));
  softmax_pv<MASK>(st, vf, ones, o, m2, l_run, k0, qrow, lg);
}

__device__ __forceinline__ void attn_group_pass(const short* Kt, const short* Vt,
                                                const short* __restrict__ Qb,
                                                short* __restrict__ Ob, int bh,
                                                int G, int w, int l, char* lds) {
  const int lg = l >> 4, ln = l & 15;
  const int qrow = G * 64 + w * 16 + ln;
  const short* Qp = Qb + ((size_t)bh * SEQ + qrow) * HD;
  const s16x8 qf0 = *(const s16x8*)(Qp + lg * 8);
  const s16x8 qf1 = *(const s16x8*)(Qp + 32 + lg * 8);
  s16x8 ones;
#pragma unroll
  for (int j = 0; j < 8; j++) ones[j] = (short)0x3F80;  // bf16 1.0

  float m2 = -3e38f, l_run = 0.f;
  f32x4 o[4];
#pragma unroll
  for (int i = 0; i < 4; i++) o[i] = f32x4{0.f, 0.f, 0.f, 0.f};

  const int nt = G + 1;  // tiles 0..G; tile G is the masked diagonal
  stage_tile(Kt, Vt, 0, lds, w, l);
  for (int t = 0; t < nt - 1; ++t) {
    stage_tile(Kt, Vt, t + 1, lds + ((t + 1) & 1) * 16384, w, l);
    asm volatile("s_waitcnt vmcnt(4)" ::: "memory");  // tile t resident
    __builtin_amdgcn_s_barrier();
    __builtin_amdgcn_sched_barrier(0);
    compute_tile<false>(lds + (t & 1) * 16384, qf0, qf1, ones, t * 64, qrow, lg,
                        ln, m2, l_run, o);
    __builtin_amdgcn_s_barrier();  // all waves done reading before overwrite
    __builtin_amdgcn_sched_barrier(0);
  }
  asm volatile("s_waitcnt vmcnt(0)" ::: "memory");
  __builtin_amdgcn_s_barrier();
  __builtin_amdgcn_sched_barrier(0);
  compute_tile<true>(lds + ((nt - 1) & 1) * 16384, qf0, qf1, ones, (nt - 1) * 64,
                     qrow, lg, ln, m2, l_run, o);
  __builtin_amdgcn_s_barrier();
  __builtin_amdgcn_sched_barrier(0);

  const float inv = 1.0f / l_run;
  const int bb = bh >> 4, hh = bh & 15;
  const size_t orow = (size_t)(bb * SEQ + qrow) * HID + hh * HD;
#pragma unroll
  for (int mt = 0; mt < 4; mt++) {
    s16x4 ov;
#pragma unroll
    for (int r = 0; r < 4; r++) ov[r] = f2bf(o[mt][r] * inv);
    *(s16x4*)(Ob + orow + mt * 16 + lg * 4) = ov;
  }
}

__global__ __launch_bounds__(256) void attn_kernel(const short* __restrict__ Qb,
                                                   const short* __restrict__ Kg,
                                                   const short* __restrict__ Vg,
                                                   short* __restrict__ Ob) {
  __shared__ char lds[32768];  // 2 buffers x (8KB K + 8KB V)
  // XCD swizzle: XCD k owns 64 consecutive logical blocks (4 heads).
  const int bid = blockIdx.x;
  const int L = (bid & 7) * 64 + (bid >> 3);
  const int bh = L >> 4, g = L & 15;
  const int w = threadIdx.x >> 6, l = threadIdx.x & 63;
  const short* Kt = Kg + (size_t)bh * (SEQ * HD);
  const short* Vt = Vg + (size_t)bh * (SEQ * HD);
  attn_group_pass(Kt, Vt, Qb, Ob, bh, g, w, l, lds);       // short pass
  attn_group_pass(Kt, Vt, Qb, Ob, bh, 31 - g, w, l, lds);  // long pass
}

// ---------------- launch ----------------
extern "C" void kernel_launch(void* const* d_in, const int* in_sizes, int n_in,
                              void* d_out, int out_size, void* d_ws,
                              size_t ws_size, hipStream_t stream) {
  const float* X = (const float*)d_in[0];
  // d_in[1] = mask (causal, implemented directly)
  const float* Wq = (const float*)d_in[2];
  const float* bq = (const float*)d_in[3];
  const float* Wk = (const float*)d_in[4];
  const float* bk = (const float*)d_in[5];
  const float* Wv = (const float*)d_in[6];
  const float* bv = (const float*)d_in[7];
  const float* Wo = (const float*)d_in[8];
  const float* bo = (const float*)d_in[9];
  float* out = (float*)d_out;

  char* ws = (char*)d_ws;
  short* Xb = (short*)(ws);                  // 8 MB  [4096][1024]
  short* Wtall = (short*)(ws + (8u << 20));  // 8 MB  (Wq|Wk|Wv|Wo)^T bf16
  short* Qb = (short*)(ws + (16u << 20));    // 8 MB  [32][2048][64] (pre-scaled)
  short* Kg = (short*)(ws + (24u << 20));    // 8 MB  [32][32 tiles][64x64 image]
  short* Vg = (short*)(ws + (32u << 20));    // 8 MB  [32][32 tiles][64x64 image]
  short* Ob = (short*)(ws + (40u << 20));    // 8 MB  [4096][1024]
  short* Wto = Wtall + (3u << 20);

  prep_kernel<<<dim3(32, 32, 5), 256, 0, stream>>>(X, Wq, Wk, Wv, Wo, Xb, Wtall);

  gemm_bf16<0, 4><<<dim3(24, 32), 256, 0, stream>>>(Xb, Wtall, bq, bk, bv, Qb,
                                                    Kg, Vg, nullptr);
  attn_kernel<<<512, 256, 0, stream>>>(Qb, Kg, Vg, Ob);
  gemm_bf16<1, 2><<<dim3(8, 64), 256, 0, stream>>>(Ob, Wto, bo, nullptr, nullptr,
                                                   nullptr, nullptr, nullptr,
                                                   out);
}